// Round 4
// baseline (83.815 us; speedup 1.0000x reference)
//
#include <hip/hip_runtime.h>
#include <math.h>

// ParabolicPool1DFast: B=32, C=64, L=4096, KS=7, STRIDE=2, HALF=3.
//
// Reference semantics (verified absmax 0.0 in rounds 1 & 3):
//   dil[b,c,l] = max_{z=-3..3} f[b,c,l+z] - z^2/(4*t[c])   (-inf outside [0,L))
//   out[b,c,i] = dil_flat[(b + c) + 2*i]    (faithful as_strided gather)
// Only dil_flat[0..4189) is consumed (rows (0,0) and (0,1) of f).
//
// Round-4: drop the per-block LDS table + barrier entirely. Block r (one
// output row, base = bi+ci block-uniform) has thread tid produce the 8
// outputs i = 8*tid..8*tid+7 directly in registers: q = base+16*tid+2s,
// taps f[q+z] -> a 21-float window covered by 6 aligned float4 loads
// (f row 0 is 16 KB -> L1-resident). Window alignment offset (base+1)&3 is
// block-uniform -> uniform 4-way switch keeps indexing constant. Border and
// row-seam lanes (~3 per block) take a guarded scalar slow path.

#define THREADS 256
#define NBLOCKS 2048            // == number of output rows (32*64)

template<int OFF>
__device__ __forceinline__ void compute8(const float w[24], const float a0,
                                         float v[8]) {
#pragma unroll
    for (int s = 0; s < 8; ++s) {
        const int c = OFF + 3 + 2 * s;          // center index in w
        const float m1 = fmaxf(w[c - 1], w[c + 1]);
        const float m2 = fmaxf(w[c - 2], w[c + 2]);
        const float m3 = fmaxf(w[c - 3], w[c + 3]);
        v[s] = fmaxf(fmaxf(w[c], m1 - a0),
                     fmaxf(m2 - 4.0f * a0, m3 - 9.0f * a0));
    }
}

__global__ __launch_bounds__(THREADS) void ParabolicPool1DFast_kernel(
    const float* __restrict__ f,   // [32,64,4096]; only rows (0,0),(0,1) used
    const float* __restrict__ t,   // [64]; only t[0], t[1] used
    float* __restrict__ out)       // [32,64,2048] flat
{
    const int tid  = threadIdx.x;
    const int r    = (int)blockIdx.x;          // output row = bi*64 + ci
    const int base = (r >> 6) + (r & 63);      // bi + ci, in [0,94], block-uniform
    const float a0 = 0.25f / t[0];

    const int Q   = base + 16 * tid;           // flat index of first output's dil
    const int off = (base + 1) & 3;            // == (Q-3)&3, block-uniform
    const int A   = Q - 3 - off;               // float4-aligned window start

    float v[8];
    // fast path: whole 21-float tap window inside f row 0, aligned cover in-bounds
    const bool fastp = (A >= 0) && (A + 24 <= 4096) && (Q + 17 <= 4095);
    if (fastp) {
        const float4* f4 = (const float4*)f + (A >> 2);
        float w[24];
#pragma unroll
        for (int k = 0; k < 6; ++k) {
            const float4 x = f4[k];
            w[4 * k + 0] = x.x; w[4 * k + 1] = x.y;
            w[4 * k + 2] = x.z; w[4 * k + 3] = x.w;
        }
        switch (off) {                          // block-uniform branch
            case 0:  compute8<0>(w, a0, v); break;
            case 1:  compute8<1>(w, a0, v); break;
            case 2:  compute8<2>(w, a0, v); break;
            default: compute8<3>(w, a0, v); break;
        }
    } else {
        // borders (q<3) and the row-0/row-1 seam (q near 4096..4188)
        const float a1 = 0.25f / t[1];
#pragma unroll
        for (int s = 0; s < 8; ++s) {
            const int q = Q + 2 * s;            // <= 4188
            const int c = q >> 12;              // 0 or 1
            const int l = q & 4095;
            const float* frow = f + (c << 12);
            const float aa = c ? a1 : a0;
            float best = -INFINITY;
#pragma unroll
            for (int j = 0; j < 7; ++j) {
                const int z = j - 3;
                const int idx = l + z;
                if (idx >= 0 && idx < 4096)
                    best = fmaxf(best, frow[idx] - (float)(z * z) * aa);
            }
            v[s] = best;
        }
    }

    float* orow = out + (r << 11) + 8 * tid;
    *(float4*)(orow)     = make_float4(v[0], v[1], v[2], v[3]);
    *(float4*)(orow + 4) = make_float4(v[4], v[5], v[6], v[7]);
}

extern "C" void kernel_launch(void* const* d_in, const int* in_sizes, int n_in,
                              void* d_out, int out_size, void* d_ws, size_t ws_size,
                              hipStream_t stream) {
    const float* f = (const float*)d_in[0];   // [32,64,4096] fp32
    const float* t = (const float*)d_in[1];   // [64] fp32
    float* out = (float*)d_out;               // 4194304 fp32
    ParabolicPool1DFast_kernel<<<NBLOCKS, THREADS, 0, stream>>>(f, t, out);
}

// Round 5
// 80.777 us; speedup vs baseline: 1.0376x; 1.0376x over previous
//
#include <hip/hip_runtime.h>
#include <math.h>

// ParabolicPool1DFast: B=32, C=64, L=4096, KS=7, STRIDE=2, HALF=3.
//
// Reference semantics (verified absmax 0.0 in rounds 1, 3, 4):
//   dil[b,c,l] = max_{z=-3..3} f[b,c,l+z] - z^2/(4*t[c])   (-inf outside [0,L))
//   out[b,c,i] = dil_flat[(b + c) + 2*i]    (faithful as_strided gather)
// Only dil_flat[0..4189) is consumed (rows (0,0) and (0,1) of f).
//
// Round-5: register-direct compute (round 4) + fully-coalesced stores
// (round 3's winning pattern). 512 thr/block, one output row per block;
// thread tid -> 4 consecutive outputs i=4*tid..4*tid+3:
//   q = base + 8*tid + 2s, taps f[q-3..q+9] -> 13 floats -> 4 aligned
//   float4 loads (L1-resident 16 KB row), ~30 VALU, ONE float4 store at
//   byte offset 16*tid (lane-contiguous -> 1 KB/instr per wave; round 4's
//   32B-stride half-line stores are the suspected +4.5us regression).
// base = bi+ci is block-uniform -> alignment switch is scalar. Border/seam
// threads (2 per block) take the guarded scalar slow path.

#define THREADS 512
#define NBLOCKS 2048            // == number of output rows (32*64)

template<int OFF>
__device__ __forceinline__ void compute4(const float w[16], const float a0,
                                         float v[4]) {
#pragma unroll
    for (int s = 0; s < 4; ++s) {
        const int c = OFF + 3 + 2 * s;          // center index in w, <= 12+OFF
        const float m1 = fmaxf(w[c - 1], w[c + 1]);
        const float m2 = fmaxf(w[c - 2], w[c + 2]);
        const float m3 = fmaxf(w[c - 3], w[c + 3]);
        v[s] = fmaxf(fmaxf(w[c], m1 - a0),
                     fmaxf(m2 - 4.0f * a0, m3 - 9.0f * a0));
    }
}

__global__ __launch_bounds__(THREADS) void ParabolicPool1DFast_kernel(
    const float* __restrict__ f,   // [32,64,4096]; only rows (0,0),(0,1) used
    const float* __restrict__ t,   // [64]; only t[0], t[1] used
    float* __restrict__ out)       // [32,64,2048] flat
{
    const int tid  = threadIdx.x;
    const int r    = (int)blockIdx.x;          // output row = bi*64 + ci
    const int base = (r >> 6) + (r & 63);      // bi + ci, in [0,94], block-uniform
    const float a0 = 0.25f / t[0];

    const int Q   = base + 8 * tid;            // dil index of 1st output
    const int off = (base + 1) & 3;            // == (Q-3)&3, block-uniform
    const int A   = Q - 3 - off;               // float4-aligned window start

    float v[4];
    // fast path: taps Q-3..Q+9 in f row 0, aligned 16-float cover in-bounds
    const bool fastp = (A >= 0) && (A + 16 <= 4096) && (Q + 9 <= 4095);
    if (fastp) {
        const float4* f4 = (const float4*)f + (A >> 2);
        float w[16];
#pragma unroll
        for (int k = 0; k < 4; ++k) {
            const float4 x = f4[k];
            w[4 * k + 0] = x.x; w[4 * k + 1] = x.y;
            w[4 * k + 2] = x.z; w[4 * k + 3] = x.w;
        }
        switch (off) {                          // block-uniform branch
            case 0:  compute4<0>(w, a0, v); break;
            case 1:  compute4<1>(w, a0, v); break;
            case 2:  compute4<2>(w, a0, v); break;
            default: compute4<3>(w, a0, v); break;
        }
    } else {
        // border (Q-3 < 0) or row-0/row-1 seam (q up to 4188)
        const float a1 = 0.25f / t[1];
#pragma unroll
        for (int s = 0; s < 4; ++s) {
            const int q = Q + 2 * s;            // <= 4188
            const int c = q >> 12;              // 0 or 1
            const int l = q & 4095;
            const float* frow = f + (c << 12);
            const float aa = c ? a1 : a0;
            float best = -INFINITY;
#pragma unroll
            for (int j = 0; j < 7; ++j) {
                const int z = j - 3;
                const int idx = l + z;
                if (idx >= 0 && idx < 4096)
                    best = fmaxf(best, frow[idx] - (float)(z * z) * aa);
            }
            v[s] = best;
        }
    }

    // one fully-coalesced float4 store per thread: lane-contiguous 16B
    *(float4*)(out + (r << 11) + 4 * tid) = make_float4(v[0], v[1], v[2], v[3]);
}

extern "C" void kernel_launch(void* const* d_in, const int* in_sizes, int n_in,
                              void* d_out, int out_size, void* d_ws, size_t ws_size,
                              hipStream_t stream) {
    const float* f = (const float*)d_in[0];   // [32,64,4096] fp32
    const float* t = (const float*)d_in[1];   // [64] fp32
    float* out = (float*)d_out;               // 4194304 fp32
    ParabolicPool1DFast_kernel<<<NBLOCKS, THREADS, 0, stream>>>(f, t, out);
}